// Round 2
// baseline (800.498 us; speedup 1.0000x reference)
//
#include <hip/hip_runtime.h>
#include <math.h>

#define BB 16
#define SS 768
#define DE 16
#define HID 128
#define NROW (BB * SS)          // 12288 rows (b,i)
#define CPR 48                  // 1 KiB chunks per row (3072 float4 / 64)
#define NCHUNK (NROW * CPR)     // 589824 chunks total

// ws (float) layout:
//  [0]                       : pocket-mask layout flag (int; 1 = byte, 0 = 32-bit)
//  [16..144)                 : v_node[128] = W_node @ W_imp[0:32]
//  [144..208)                : u_e[64]     = W_e2  @ W_imp[32:64]
//  [208]                     : cterm
//  [256..12544)              : imp[NROW]
//  [12544..24832)            : dist[NROW]
//  [32768..32768+NCHUNK)     : per-chunk partial sums
//  [622592..622592+NCHUNK)   : per-chunk partial masked mins
#define WS_IMP 256
#define WS_DST (256 + NROW)
#define WS_SUM 32768
#define WS_MIN (32768 + NCHUNK)

// block 0: sniff pocket-mask layout; block 1: fold the linear head into ws.
__global__ __launch_bounds__(256) void setup_kernel(
    const unsigned int* __restrict__ pm,
    const float* __restrict__ Wn, const float* __restrict__ bn,
    const float* __restrict__ We2, const float* __restrict__ be2,
    const float* __restrict__ Wimp, const float* __restrict__ bimp,
    float* __restrict__ ws) {
    const int tid = threadIdx.x;
    if (blockIdx.x == 0) {
        __shared__ int bad;
        if (tid == 0) bad = 0;
        __syncthreads();
        for (int t = tid; t < (BB * SS) / 4; t += 256) {
            unsigned int w = pm[t];
            if (w > 1u && w != 0x3F800000u) bad = 1;  // impossible for int32 0/1 or f32 0/1
        }
        __syncthreads();
        if (tid == 0) ((int*)ws)[0] = bad;
    } else {
        if (tid < 128) {
            float s = 0.f;
            for (int c = 0; c < 32; ++c) s += Wn[tid * 32 + c] * Wimp[c];
            ws[16 + tid] = s;
        }
        if (tid < 64) {
            float s = 0.f;
            for (int c = 0; c < 32; ++c) s += We2[tid * 32 + c] * Wimp[32 + c];
            ws[144 + tid] = s;
        }
        if (tid == 0) {
            float s = bimp[0];
            for (int c = 0; c < 32; ++c) s += bn[c] * Wimp[c];
            for (int c = 0; c < 32; ++c) s += be2[c] * Wimp[32 + c];
            ws[208] = s;
        }
    }
}

// Phase A: single marching front over the whole edge buffer (fill-style
// grid-stride). Each wave owns one 1 KiB chunk (64 float4) per stride step;
// a chunk never straddles a row (3072 % 64 == 0). Wave-reduce sum + masked
// channel-0 min, write one partial pair per chunk. No atomics, no init:
// every slot is written exactly once.
__global__ __launch_bounds__(256) void edgeA_kernel(
    const float4* __restrict__ edge, const void* __restrict__ pmask,
    float* __restrict__ ws) {
    const int lane = threadIdx.x & 63;
    const int gw = (blockIdx.x * 256 + threadIdx.x) >> 6;   // global wave id
    const int nw = (gridDim.x * 256) >> 6;                  // 8192 waves
    const int flag = ((const int*)ws)[0];
    const bool ch0 = (lane & 3) == 0;

    for (int c = gw; c < NCHUNK; c += nw) {
        const float4 v = edge[((size_t)c << 6) + lane];
        float s = (v.x + v.y) + (v.z + v.w);
        float dm = INFINITY;
        if (ch0) {
            const int row = c / CPR;                  // bi
            const int cc = c - row * CPR;             // chunk within row
            const int b = row / SS;
            const int j = (cc << 4) + (lane >> 2);    // column index
            int m = flag ? (((const unsigned char*)pmask)[b * SS + j] != 0)
                         : (((const unsigned int*)pmask)[(size_t)b * SS + j] != 0u);
            if (m) dm = v.x;
        }
#pragma unroll
        for (int x = 32; x > 0; x >>= 1) {
            s += __shfl_xor(s, x, 64);
            dm = fminf(dm, __shfl_xor(dm, x, 64));
        }
        if (lane == 0) {
            ws[WS_SUM + c] = s;
            ws[WS_MIN + c] = dm;
        }
    }
}

// Phase B: one wave per row. Fold 48 partials -> row sum / row min, then the
// importance logit (nf . v_node + relu(es*We1+be1) . u_e + cterm).
__global__ __launch_bounds__(256) void edgeB_kernel(
    const float* __restrict__ nf, const float* __restrict__ seqmask,
    const float* __restrict__ We1, const float* __restrict__ be1,
    float* __restrict__ ws) {
    const int lane = threadIdx.x & 63;
    const int bi = blockIdx.x * 4 + (threadIdx.x >> 6);

    float s = (lane < CPR) ? ws[WS_SUM + bi * CPR + lane] : 0.f;
    float dm = (lane < CPR) ? ws[WS_MIN + bi * CPR + lane] : INFINITY;
#pragma unroll
    for (int x = 32; x > 0; x >>= 1) {
        s += __shfl_xor(s, x, 64);
        dm = fminf(dm, __shfl_xor(dm, x, 64));
    }

    const float es = s * (1.0f / (float)(SS * DE));
    float p = nf[(size_t)bi * HID + lane] * ws[16 + lane]
            + nf[(size_t)bi * HID + 64 + lane] * ws[16 + 64 + lane];
    float h = fmaxf(es * We1[lane] + be1[lane], 0.f);
    p += h * ws[144 + lane];
#pragma unroll
    for (int x = 32; x > 0; x >>= 1) p += __shfl_xor(p, x, 64);

    if (lane == 0) {
        float logit = p + ws[208];
        ws[WS_IMP + bi] = seqmask[bi] / (1.f + expf(-logit));
        ws[WS_DST + bi] = dm;
    }
}

__global__ __launch_bounds__(256) void final_kernel(
    const void* __restrict__ pmask, const float* __restrict__ ws,
    float* __restrict__ out) {
    const int tid = threadIdx.x;
    const int b = blockIdx.x;
    __shared__ float s_f[256];
    __shared__ int s_i[256];

    const float* imp = ws + WS_IMP;
    const float* dist = ws + WS_DST;
    const int flag = ((const int*)ws)[0];

    float psum = 0.f;
    int por = 0;
    for (int i = tid; i < SS; i += 256) {
        psum += imp[b * SS + i];
        int m = flag ? (((const unsigned char*)pmask)[b * SS + i] != 0)
                     : (((const unsigned int*)pmask)[b * SS + i] != 0u);
        por |= m;
    }
    s_f[tid] = psum;
    s_i[tid] = por;
    __syncthreads();
    for (int off = 128; off > 0; off >>= 1) {
        if (tid < off) {
            s_f[tid] += s_f[tid + off];
            s_i[tid] |= s_i[tid + off];
        }
        __syncthreads();
    }
    const float imp_mean = s_f[0] / (float)SS;
    const int haspocket = s_i[0];
    __syncthreads();

    int cnt = 0;
    for (int i = tid; i < SS; i += 256) {
        int m = flag ? (((const unsigned char*)pmask)[b * SS + i] != 0)
                     : (((const unsigned int*)pmask)[b * SS + i] != 0u);
        float d = dist[b * SS + i];
        bool core = d < 6.0f;
        bool shell = (d >= 6.0f) && (d < 10.0f) && (imp[b * SS + i] > imp_mean);
        cnt += (m || core || shell) ? 1 : 0;
    }
    s_i[tid] = cnt;
    __syncthreads();
    for (int off = 128; off > 0; off >>= 1) {
        if (tid < off) s_i[tid] += s_i[tid + off];
        __syncthreads();
    }
    if (tid == 0) {
        float chunk;
        if (haspocket) {
            float ml = fminf((float)s_i[0], 256.f);   // merged_len clamp
            chunk = fminf(fmaxf(ml, 64.f), 256.f);    // adj=64, MAX_SEQ_LEN=256
        } else {
            chunk = fminf(fmaxf(64.f * imp_mean, 32.f), 128.f);
        }
        out[b] = chunk;
        if (b == 0) out[BB] = 256.f;                  // MAX_SEQ_LEN output
    }
}

extern "C" void kernel_launch(void* const* d_in, const int* in_sizes, int n_in,
                              void* d_out, int out_size, void* d_ws, size_t ws_size,
                              hipStream_t stream) {
    const float* nf = (const float*)d_in[0];
    const float4* edge = (const float4*)d_in[1];
    const float* seqmask = (const float*)d_in[2];
    const void* pmask = d_in[3];
    const float* Wn = (const float*)d_in[4];
    const float* bn = (const float*)d_in[5];
    const float* We1 = (const float*)d_in[6];
    const float* be1 = (const float*)d_in[7];
    const float* We2 = (const float*)d_in[8];
    const float* be2 = (const float*)d_in[9];
    const float* Wimp = (const float*)d_in[10];
    const float* bimp = (const float*)d_in[11];
    float* ws = (float*)d_ws;
    float* out = (float*)d_out;

    setup_kernel<<<2, 256, 0, stream>>>((const unsigned int*)pmask,
                                        Wn, bn, We2, be2, Wimp, bimp, ws);
    edgeA_kernel<<<2048, 256, 0, stream>>>(edge, pmask, ws);
    edgeB_kernel<<<NROW / 4, 256, 0, stream>>>(nf, seqmask, We1, be1, ws);
    final_kernel<<<BB, 256, 0, stream>>>(pmask, ws, out);
}